// Round 13
// baseline (5390.358 us; speedup 1.0000x reference)
//
#include <hip/hip_runtime.h>
#include <hip/hip_bf16.h>

#define NN 20000
#define EE 320000
#define GG 64
#define HH 280
#define NFF 5
#define EFF 4
#define LL 3
#define ZZ 64
#define BN_EPS 1e-5f

typedef __hip_bfloat16 bf;
typedef unsigned short ush;
typedef __attribute__((ext_vector_type(8))) short v8s;
typedef __attribute__((ext_vector_type(4))) float v4f;

__device__ __forceinline__ float us2f(ush u) {
  return __uint_as_float(((unsigned)u) << 16);
}
__device__ __forceinline__ ush f2us(float v) {
  bf b = __float2bfloat16(v);
  return *reinterpret_cast<ush*>(&b);
}
__device__ __forceinline__ int clampi(int v, int hi) {
  return v < 0 ? 0 : (v >= hi ? hi - 1 : v);
}

// ---------------------------------------------------------------------------
// dtype probe (x ~ N(0,1)): fp32 read as bf16 words -> implausible exponents
// ---------------------------------------------------------------------------
__global__ void probe_k(const void* __restrict__ x, int* __restrict__ flag) {
  __shared__ int sh[256];
  int tid = threadIdx.x;
  int cnt = 0;
  for (int i = tid; i < 2048; i += 256) {
    ush w = ((const ush*)x)[i];
    unsigned e = (w >> 7) & 0xFF;
    if (w != 0 && (e < 87 || e > 167)) cnt++;
  }
  sh[tid] = cnt;
  __syncthreads();
  for (int o = 128; o > 0; o >>= 1) {
    if (tid < o) sh[tid] += sh[tid + o];
    __syncthreads();
  }
  if (tid == 0) *flag = (sh[0] > 64) ? 1 : 0;
}

__global__ void convert_k(const void* __restrict__ src, float* __restrict__ dst,
                          int n, const int* __restrict__ flag) {
  int i = blockIdx.x * 256 + threadIdx.x;
  if (i < n) {
    if (*flag)
      dst[i] = ((const float*)src)[i];
    else
      dst[i] = us2f(((const ush*)src)[i]);
  }
}

// ---------------------------------------------------------------------------
// weight transpose builders (fp32 -> bf16 B^T padded with zeros)
// ---------------------------------------------------------------------------
__global__ void wt_ab_k(const float* __restrict__ W, ush* __restrict__ O) {
  int i = blockIdx.x * 256 + threadIdx.x;
  if (i >= 3 * 576 * 288) return;
  int l = i / 165888, r = i % 165888;
  int n = r / 288, k = r % 288;
  float v = 0.f;
  if (n < 560 && k < 280)
    v = (n < 280) ? W[(size_t)l * 157920 + (size_t)k * 280 + n]
                  : W[(size_t)l * 157920 + (size_t)(280 + k) * 280 + (n - 280)];
  O[i] = f2us(v);
}
__global__ void wt_sq_k(const float* __restrict__ W, ush* __restrict__ O) {
  int i = blockIdx.x * 256 + threadIdx.x;
  if (i >= 3 * 320 * 288) return;
  int l = i / 92160, r = i % 92160;
  int n = r / 288, k = r % 288;
  float v = (n < 280 && k < 280) ? W[(size_t)l * 78400 + (size_t)k * 280 + n] : 0.f;
  O[i] = f2us(v);
}
__global__ void wt_u1_k(const float* __restrict__ W, ush* __restrict__ O) {
  int i = blockIdx.x * 256 + threadIdx.x;
  if (i >= 3 * 320 * 576) return;
  int l = i / 184320, r = i % 184320;
  int n = r / 576, k = r % 576;
  float v = (n < 280 && k < 560) ? W[(size_t)l * 156800 + (size_t)k * 280 + n] : 0.f;
  O[i] = f2us(v);
}

// ---------------------------------------------------------------------------
// MFMA bf16 GEMM (best measured): BM=128, BN=64. B-tile staged in LDS once
// per 288-K-tile; A-frags global->VGPR direct, 18 in flight; no barriers in
// K-loop. Optional fused column sum/sumsq stats.
// ---------------------------------------------------------------------------
struct MG {
  const ush* A;
  const ush* Bt;
  const float* bias;
  void* C;
  float* stats;
  int M, K, Nn, lda, ldb, ldc;
};

template <int CB, int ST>
__global__ __launch_bounds__(256) void mgemm_k(MG g) {
  __shared__ ush Bs[64][296];
  auto red = (float(*)[64])Bs;
  int t = threadIdx.x;
  int n0 = blockIdx.x * 64, m0 = blockIdx.y * 128;
  int lane = t & 63, wv = t >> 6;
  int lrow = lane & 15, quad = lane >> 4;
  int br = t >> 2;
  int bc = (t & 3) * 72;
  v4f acc[2][4];
#pragma unroll
  for (int gi = 0; gi < 2; ++gi)
#pragma unroll
    for (int ci = 0; ci < 4; ++ci) acc[gi][ci] = (v4f){0.f, 0.f, 0.f, 0.f};

  const ush* Arow[2];
  bool av[2];
#pragma unroll
  for (int gi = 0; gi < 2; ++gi) {
    int gm = m0 + (wv << 5) + (gi << 4) + lrow;
    av[gi] = gm < g.M;
    Arow[gi] = g.A + (size_t)gm * g.lda + (quad << 3);
  }
  const ush* Brow = g.Bt + (size_t)(n0 + br) * g.ldb + bc;
  uint4 zz = {0, 0, 0, 0};

  int ntile = g.K / 288;
  for (int tile = 0; tile < ntile; ++tile) {
    int k0 = tile * 288;
    uint4 aR[2][9];
#pragma unroll
    for (int kt = 0; kt < 9; ++kt)
#pragma unroll
      for (int gi = 0; gi < 2; ++gi)
        aR[gi][kt] = av[gi] ? *(const uint4*)(Arow[gi] + k0 + (kt << 5)) : zz;
    if (tile) __syncthreads();
#pragma unroll
    for (int i = 0; i < 9; ++i)
      *(uint4*)&Bs[br][bc + (i << 3)] = *(const uint4*)(Brow + k0 + (i << 3));
    __syncthreads();
#pragma unroll
    for (int kt = 0; kt < 9; ++kt) {
      v8s bq[4];
#pragma unroll
      for (int ci = 0; ci < 4; ++ci)
        bq[ci] = *(const v8s*)&Bs[(ci << 4) + lrow][(kt << 5) + (quad << 3)];
#pragma unroll
      for (int gi = 0; gi < 2; ++gi) {
        v8s af = *(v8s*)&aR[gi][kt];
#pragma unroll
        for (int ci = 0; ci < 4; ++ci)
          acc[gi][ci] = __builtin_amdgcn_mfma_f32_16x16x32_bf16(
              af, bq[ci], acc[gi][ci], 0, 0, 0);
      }
    }
  }

  float bj[4];
#pragma unroll
  for (int ci = 0; ci < 4; ++ci) {
    int gn = n0 + (ci << 4) + lrow;
    bj[ci] = (g.bias && gn < g.Nn) ? g.bias[gn] : 0.f;
  }
#pragma unroll
  for (int gi = 0; gi < 2; ++gi)
#pragma unroll
    for (int ci = 0; ci < 4; ++ci)
#pragma unroll
      for (int r = 0; r < 4; ++r) {
        int gm = m0 + (wv << 5) + (gi << 4) + (quad << 2) + r;
        int gn = n0 + (ci << 4) + lrow;
        float v = acc[gi][ci][r] + bj[ci];
        bool ok = (gm < g.M) && (gn < g.Nn);
        if (ok) {
          size_t idx = (size_t)gm * g.ldc + gn;
          if (CB)
            ((ush*)g.C)[idx] = f2us(v);
          else
            ((float*)g.C)[idx] = v;
        }
        acc[gi][ci][r] = ok ? v : 0.f;
      }
  if (ST) {
    int rowg = (wv << 2) | quad;
    __syncthreads();
#pragma unroll
    for (int ci = 0; ci < 4; ++ci) {
      float s = 0.f;
#pragma unroll
      for (int gi = 0; gi < 2; ++gi)
#pragma unroll
        for (int r = 0; r < 4; ++r) s += acc[gi][ci][r];
      red[rowg][(ci << 4) | lrow] = s;
    }
    __syncthreads();
    if (t < 64) {
      float s = 0.f;
#pragma unroll
      for (int r = 0; r < 16; ++r) s += red[r][t];
      int gn = n0 + t;
      if (gn < g.Nn) atomicAdd(&g.stats[gn], s);
    }
    __syncthreads();
#pragma unroll
    for (int ci = 0; ci < 4; ++ci) {
      float s = 0.f;
#pragma unroll
      for (int gi = 0; gi < 2; ++gi)
#pragma unroll
        for (int r = 0; r < 4; ++r) s += acc[gi][ci][r] * acc[gi][ci][r];
      red[rowg][(ci << 4) | lrow] = s;
    }
    __syncthreads();
    if (t < 64) {
      float s = 0.f;
#pragma unroll
      for (int r = 0; r < 16; ++r) s += red[r][t];
      int gn = n0 + t;
      if (gn < g.Nn) atomicAdd(&g.stats[HH + gn], s);
    }
  }
}

// ---------------------------------------------------------------------------
// small fp32 GEMM (input layer, final head). 64x64 tile.
// ---------------------------------------------------------------------------
__global__ __launch_bounds__(256) void gemm_small_k(
    const float* __restrict__ A, const float* __restrict__ B,
    const float* __restrict__ bias, void* __restrict__ C,
    const int* __restrict__ flag, int M, int K, int Nn, int lda, int ldb,
    int ldc, int outmode) {
  __shared__ alignas(16) float As[16][68];
  __shared__ alignas(16) float Bsm[16][68];
  int tid = threadIdx.x;
  int n0 = blockIdx.x * 64, m0 = blockIdx.y * 64;
  int tx = tid & 15, ty = tid >> 4;
  int am = tid >> 2, akq = (tid & 3) << 2;
  int bk = tid >> 4, bn = (tid & 15) << 2;
  float acc[4][4] = {};
  int gmA = m0 + am;
  int nkt = (K + 15) >> 4;
  for (int kt = 0; kt < nkt; ++kt) {
    int k0 = kt << 4;
#pragma unroll
    for (int i = 0; i < 4; ++i) {
      int gk = k0 + akq + i;
      As[akq + i][am] = (gmA < M && gk < K) ? A[(size_t)gmA * lda + gk] : 0.f;
    }
    {
      int gk = k0 + bk;
      bool kin = gk < K;
#pragma unroll
      for (int j = 0; j < 4; ++j) {
        int gn = n0 + bn + j;
        Bsm[bk][bn + j] = (kin && gn < Nn) ? B[(size_t)gk * ldb + gn] : 0.f;
      }
    }
    __syncthreads();
#pragma unroll
    for (int kk = 0; kk < 16; ++kk) {
      float4 a4 = *(const float4*)&As[kk][ty << 2];
      float4 b4 = *(const float4*)&Bsm[kk][tx << 2];
      float av[4] = {a4.x, a4.y, a4.z, a4.w};
      float bv[4] = {b4.x, b4.y, b4.z, b4.w};
#pragma unroll
      for (int i = 0; i < 4; ++i)
#pragma unroll
        for (int j = 0; j < 4; ++j) acc[i][j] = fmaf(av[i], bv[j], acc[i][j]);
    }
    __syncthreads();
  }
  int ofl = outmode ? *flag : -1;
#pragma unroll
  for (int i = 0; i < 4; ++i) {
    int gm = m0 + (ty << 2) + i;
    if (gm < M) {
#pragma unroll
      for (int j = 0; j < 4; ++j) {
        int gn = n0 + (tx << 2) + j;
        if (gn < Nn) {
          float v = acc[i][j] + (bias ? bias[gn] : 0.f);
          size_t idx = (size_t)gm * ldc + gn;
          if (outmode == 0)
            ((float*)C)[idx] = v;
          else if (ofl)
            ((float*)C)[idx] = v;
          else
            ((ush*)C)[idx] = f2us(v);
        }
      }
    }
  }
}

// ---------------------------------------------------------------------------
// SINGLE gather pass: raw tmp1 (incl b1) -> T1 (CSR row order, bf16) with
// fused BN1 sum/sumsq stats (fp32, pre-rounding). 256 edges/block.
// ---------------------------------------------------------------------------
__global__ __launch_bounds__(256) void build_raw_k(
    const int* __restrict__ eids, const int* __restrict__ dst,
    const int* __restrict__ src, const float* __restrict__ ea,
    const ush* __restrict__ Pq, const float* __restrict__ W1c,
    const float* __restrict__ b1, ush* __restrict__ T1,
    float* __restrict__ stats) {
  __shared__ int dstl[256], srcl[256];
  __shared__ float4 eal[256];
  __shared__ float w1cs[4 * HH];
  __shared__ float b1s[HH];
  int tid = threadIdx.x;
  int e0 = blockIdx.x * 256;
  {
    int e = clampi(eids[e0 + tid], EE);
    dstl[tid] = clampi(dst[e], NN);
    srcl[tid] = clampi(src[e], NN);
    eal[tid] = *(const float4*)(ea + (size_t)e * 4);
  }
  for (int i = tid; i < 4 * HH; i += 256) w1cs[i] = W1c[i];
  for (int i = tid; i < HH; i += 256) b1s[i] = b1[i];
  __syncthreads();
  int c0 = tid, c1 = tid + 256;
  bool has1 = c1 < HH;
  float w0x = w1cs[c0], w0y = w1cs[HH + c0], w0z = w1cs[2 * HH + c0],
        w0w = w1cs[3 * HH + c0], b0v = b1s[c0];
  float w1x = 0.f, w1y = 0.f, w1z = 0.f, w1w = 0.f, b1v = 0.f;
  if (has1) {
    w1x = w1cs[c1]; w1y = w1cs[HH + c1]; w1z = w1cs[2 * HH + c1];
    w1w = w1cs[3 * HH + c1]; b1v = b1s[c1];
  }
  float s0 = 0.f, q0 = 0.f, s1 = 0.f, q1 = 0.f;
  for (int e = 0; e < 256; e += 4) {
    ush pd[4], ps[4], pd2[4], ps2[4];
#pragma unroll
    for (int j = 0; j < 4; ++j) {
      size_t bd = (size_t)dstl[e + j] * 576, bs = (size_t)srcl[e + j] * 576 + 280;
      pd[j] = Pq[bd + c0];
      ps[j] = Pq[bs + c0];
      if (has1) {
        pd2[j] = Pq[bd + c1];
        ps2[j] = Pq[bs + c1];
      }
    }
#pragma unroll
    for (int j = 0; j < 4; ++j) {
      size_t orow = (size_t)(e0 + e + j) * 288;
      float4 ev = eal[e + j];
      float tv = us2f(pd[j]) + us2f(ps[j]) + ev.x * w0x + ev.y * w0y +
                 ev.z * w0z + ev.w * w0w + b0v;
      s0 += tv;
      q0 += tv * tv;
      T1[orow + c0] = f2us(tv);
      if (has1) {
        float t2 = us2f(pd2[j]) + us2f(ps2[j]) + ev.x * w1x + ev.y * w1y +
                   ev.z * w1z + ev.w * w1w + b1v;
        s1 += t2;
        q1 += t2 * t2;
        T1[orow + c1] = f2us(t2);
      }
    }
  }
  atomicAdd(&stats[c0], s0);
  atomicAdd(&stats[HH + c0], q0);
  if (has1) {
    atomicAdd(&stats[c1], s1);
    atomicAdd(&stats[HH + c1], q1);
  }
}

// streaming BN1 apply + relu, in place on T1 (uint4 = 8 ush per thread).
// group 35 (cols 280-287) is pad: skipped (garbage stays finite poison).
__global__ __launch_bounds__(256) void bn_apply_k(ush* __restrict__ T1,
                                                  const float* __restrict__ scale,
                                                  const float* __restrict__ shift) {
  size_t idx = (size_t)blockIdx.x * 256 + threadIdx.x;  // over EE*36 groups
  int g = (int)(idx % 36);
  if (g == 35) return;
  int c0 = g << 3;
  uint4* p = (uint4*)T1 + idx;
  uint4 v = *p;
  ush* pv = (ush*)&v;
#pragma unroll
  for (int j = 0; j < 8; ++j) {
    float x = fmaf(scale[c0 + j], us2f(pv[j]), shift[c0 + j]);
    pv[j] = f2us(x > 0.f ? x : 0.f);
  }
  *p = v;
}

// ---------------------------------------------------------------------------
// BN1 stats over edges (fallback chunked path)
// ---------------------------------------------------------------------------
__global__ __launch_bounds__(256) void edge_stats_k(
    const int* __restrict__ eids, const int* __restrict__ dst,
    const int* __restrict__ src, const float* __restrict__ ea,
    const ush* __restrict__ Pq, const float* __restrict__ W1c,
    const float* __restrict__ b1, float* __restrict__ stats) {
  __shared__ int dstl[256], srcl[256];
  __shared__ float4 eal[256];
  __shared__ float w1cs[4 * HH];
  __shared__ float b1s[HH];
  int tid = threadIdx.x;
  int e0 = blockIdx.x * 256;
  {
    int e = clampi(eids[e0 + tid], EE);
    dstl[tid] = clampi(dst[e], NN);
    srcl[tid] = clampi(src[e], NN);
    eal[tid] = *(const float4*)(ea + (size_t)e * 4);
  }
  for (int i = tid; i < 4 * HH; i += 256) w1cs[i] = W1c[i];
  for (int i = tid; i < HH; i += 256) b1s[i] = b1[i];
  __syncthreads();
  int c0 = tid, c1 = tid + 256;
  bool has1 = c1 < HH;
  float s0 = 0.f, q0 = 0.f, s1 = 0.f, q1 = 0.f;
  for (int e = 0; e < 256; ++e) {
    int d = dstl[e], sn = srcl[e];
    float4 ev = eal[e];
    {
      float raw = us2f(Pq[(size_t)d * 576 + c0]) + us2f(Pq[(size_t)sn * 576 + 280 + c0]);
      float r = ev.x * w1cs[c0] + ev.y * w1cs[HH + c0] +
                ev.z * w1cs[2 * HH + c0] + ev.w * w1cs[3 * HH + c0];
      float tv = raw + r + b1s[c0];
      s0 += tv; q0 += tv * tv;
    }
    if (has1) {
      float raw = us2f(Pq[(size_t)d * 576 + c1]) + us2f(Pq[(size_t)sn * 576 + 280 + c1]);
      float r = ev.x * w1cs[c1] + ev.y * w1cs[HH + c1] +
                ev.z * w1cs[2 * HH + c1] + ev.w * w1cs[3 * HH + c1];
      float tv = raw + r + b1s[c1];
      s1 += tv; q1 += tv * tv;
    }
  }
  atomicAdd(&stats[c0], s0);
  atomicAdd(&stats[HH + c0], q0);
  if (has1) {
    atomicAdd(&stats[c1], s1);
    atomicAdd(&stats[HH + c1], q1);
  }
}

__global__ void bn_finalize_k(const float* __restrict__ stats, float cnt,
                              const float* __restrict__ gw,
                              const float* __restrict__ bw,
                              const float* __restrict__ extra,
                              float* __restrict__ scale,
                              float* __restrict__ shift) {
  int c = threadIdx.x;
  if (c < HH) {
    float m = stats[c] / cnt;
    float v = stats[HH + c] / cnt - m * m;
    v = v < 0.f ? 0.f : v;
    float r = rsqrtf(v + BN_EPS);
    float sc = gw[c] * r;
    float sh = bw[c] - sc * m + (extra ? sc * extra[c] : 0.f);
    scale[c] = sc;
    shift[c] = sh;
  }
}

// ---------------------------------------------------------------------------
// CSR build over dst
// ---------------------------------------------------------------------------
__global__ void hist_k(const int* __restrict__ dst, int* __restrict__ counts) {
  int e = blockIdx.x * 256 + threadIdx.x;
  if (e < EE) atomicAdd(&counts[clampi(dst[e], NN)], 1);
}

__global__ __launch_bounds__(1024) void scan_k(const int* __restrict__ counts,
                                               int* __restrict__ offs, int n) {
  __shared__ int buf[1024];
  __shared__ int running;
  int tid = threadIdx.x;
  if (tid == 0) running = 0;
  __syncthreads();
  for (int base = 0; base < n; base += 1024) {
    int v = (base + tid < n) ? counts[base + tid] : 0;
    buf[tid] = v;
    __syncthreads();
    for (int off = 1; off < 1024; off <<= 1) {
      int t = (tid >= off) ? buf[tid - off] : 0;
      __syncthreads();
      buf[tid] += t;
      __syncthreads();
    }
    int incl = buf[tid];
    if (base + tid < n) offs[base + tid] = running + incl - v;
    __syncthreads();
    if (tid == 1023) running += incl;
    __syncthreads();
  }
  if (tid == 0) offs[n] = running;
}

__global__ void fill_k(const int* __restrict__ dst, const int* __restrict__ offs,
                       int* __restrict__ cursor, int* __restrict__ eids) {
  int e = blockIdx.x * 256 + threadIdx.x;
  if (e < EE) {
    int n = clampi(dst[e], NN);
    int pos = atomicAdd(&cursor[n], 1);
    int idx = offs[n] + pos;
    if (idx >= 0 && idx < EE) eids[idx] = e;
  }
}

// ---------------------------------------------------------------------------
// T1 builder (fallback chunked path): normalized bn1(T1) bf16
// ---------------------------------------------------------------------------
__global__ __launch_bounds__(256) void build_t1_k(
    const int* __restrict__ eids, const int* __restrict__ dst,
    const int* __restrict__ src, const float* __restrict__ ea,
    const ush* __restrict__ Pq, const float* __restrict__ W1c,
    const float* __restrict__ sc, const float* __restrict__ sh,
    ush* __restrict__ T1, int cb) {
  __shared__ float scs[HH], shs[HH], w1[4 * HH];
  int t = threadIdx.x;
  for (int i = t; i < HH; i += 256) { scs[i] = sc[i]; shs[i] = sh[i]; }
  for (int i = t; i < 4 * HH; i += 256) w1[i] = W1c[i];
  __syncthreads();
  int base = blockIdx.x * 32;
  int c2 = t + 256;
  bool h2 = c2 < HH;
  for (int i = 0; i < 32; ++i) {
    int r = cb + base + i;
    int e = clampi(eids[r], EE);
    int d = clampi(dst[e], NN), s = clampi(src[e], NN);
    float4 ev = *(const float4*)(ea + (size_t)e * 4);
    size_t pd = (size_t)d * 576, ps = (size_t)s * 576 + 280;
    size_t orow = (size_t)(base + i) * 288;
    {
      int c = t;
      float v = us2f(Pq[pd + c]) + us2f(Pq[ps + c]) + ev.x * w1[c] +
                ev.y * w1[HH + c] + ev.z * w1[2 * HH + c] + ev.w * w1[3 * HH + c];
      v = fmaf(scs[c], v, shs[c]);
      T1[orow + c] = f2us(v > 0.f ? v : 0.f);
    }
    if (h2) {
      int c = c2;
      float v = us2f(Pq[pd + c]) + us2f(Pq[ps + c]) + ev.x * w1[c] +
                ev.y * w1[HH + c] + ev.z * w1[2 * HH + c] + ev.w * w1[3 * HH + c];
      v = fmaf(scs[c], v, shs[c]);
      T1[orow + c] = f2us(v > 0.f ? v : 0.f);
    }
  }
}

// ---------------------------------------------------------------------------
// CSR-streamed aggregate: agg[n][c] += sum_{r in [rs,re)∩[e0,e1)} relu(bn2(tmp2))
// ---------------------------------------------------------------------------
__global__ __launch_bounds__(256) void aggregate_k(
    const int* __restrict__ offs, const ush* __restrict__ tmp2,
    const float* __restrict__ scale, const float* __restrict__ shift,
    float* __restrict__ agg, int e0, int e1) {
  int n = blockIdx.x;
  int rs = offs[n], re = offs[n + 1];
  if (rs < e0) rs = e0;
  if (re > e1) re = e1;
  if (rs >= re) return;
  int t = threadIdx.x;
  int c2 = t + 256;
  bool h2 = c2 < HH;
  float a0 = 0.f, a1 = 0.f;
  float sc0 = scale[t], sh0 = shift[t];
  float sc1 = h2 ? scale[c2] : 0.f, sh1 = h2 ? shift[c2] : 0.f;
  for (int r = rs; r < re; ++r) {
    const ush* row = tmp2 + (size_t)(r - e0) * HH;
    float v0 = fmaf(sc0, us2f(row[t]), sh0);
    a0 += v0 > 0.f ? v0 : 0.f;
    if (h2) {
      float v1 = fmaf(sc1, us2f(row[c2]), sh1);
      a1 += v1 > 0.f ? v1 : 0.f;
    }
  }
  agg[(size_t)n * HH + t] += a0;
  if (h2) agg[(size_t)n * HH + c2] += a1;
}

// ---------------------------------------------------------------------------
// elementwise helpers
// ---------------------------------------------------------------------------
__global__ void hb_k(const float* __restrict__ h, ush* __restrict__ hcat) {
  int i = blockIdx.x * 256 + threadIdx.x;
  if (i < NN * HH) {
    int n = i / HH, c = i % HH;
    hcat[(size_t)n * 576 + c] = f2us(h[i]);
  }
}
__global__ void agg2hcat_k(const float* __restrict__ agg, ush* __restrict__ hcat) {
  int i = blockIdx.x * 256 + threadIdx.x;
  if (i < NN * HH) {
    int n = i / HH, c = i % HH;
    hcat[(size_t)n * 576 + 280 + c] = f2us(agg[i]);
  }
}
__global__ void u2a_k(const float* __restrict__ u1, const float* __restrict__ sc,
                      const float* __restrict__ sh, ush* __restrict__ u2A) {
  int i = blockIdx.x * 256 + threadIdx.x;
  if (i < NN * HH) {
    int n = i / HH, c = i % HH;
    float v = fmaf(sc[c], u1[i], sh[c]);
    u2A[(size_t)n * 288 + c] = f2us(v > 0.f ? v : 0.f);
  }
}
__global__ void residual_k(float* __restrict__ h, const float* __restrict__ u2,
                           const float* __restrict__ scale,
                           const float* __restrict__ shift) {
  int i = blockIdx.x * 256 + threadIdx.x;
  if (i < NN * HH) {
    int c = i % HH;
    float v = fmaf(scale[c], u2[i], shift[c]);
    h[i] += v > 0.f ? v : 0.f;
  }
}

__device__ __forceinline__ int lowerb(const int* a, int n, int key) {
  int lo = 0, hi = n;
  while (lo < hi) {
    int mid = (lo + hi) >> 1;
    if (a[mid] < key) lo = mid + 1; else hi = mid;
  }
  return lo;
}

__global__ __launch_bounds__(256) void pool_k(const float* __restrict__ h,
                                              const int* __restrict__ batch,
                                              float* __restrict__ pooled) {
  __shared__ float red[4][56];
  int gid = blockIdx.x, cc = blockIdx.y;
  int start = lowerb(batch, NN, gid);
  int end = lowerb(batch, NN, gid + 1);
  int cnt = end - start;
  float inv = 1.f / (float)(cnt > 1 ? cnt : 1);
  int grp = threadIdx.x >> 6, ci = threadIdx.x & 63;
  if (ci < 56) {
    int col = cc * 56 + ci;
    float s = 0.f;
    for (int n = start + grp; n < end; n += 4) s += h[(size_t)n * HH + col];
    red[grp][ci] = s;
  }
  __syncthreads();
  if (threadIdx.x < 56) {
    float s = red[0][threadIdx.x] + red[1][threadIdx.x] +
              red[2][threadIdx.x] + red[3][threadIdx.x];
    pooled[(size_t)gid * HH + cc * 56 + threadIdx.x] = s * inv;
  }
}

// ---------------------------------------------------------------------------
extern "C" void kernel_launch(void* const* d_in, const int* in_sizes, int n_in,
                              void* d_out, int out_size, void* d_ws,
                              size_t ws_size, hipStream_t stream) {
  const int* eidx = (const int*)d_in[2];
  const int* batch = (const int*)d_in[3];
  const int* srcp = eidx;
  const int* dstp = eidx + EE;
  size_t NH = (size_t)NN * HH;

  // ---- workspace layout ----
  float* w0 = (float*)d_ws;
  size_t off = 0;
  auto alloc = [&](size_t n) {
    float* p = w0 + off;
    off += (n + 3) & ~(size_t)3;
    return p;
  };
  int* flag = (int*)alloc(4);
  float* cx = alloc(100000);
  float* cea = alloc(1280000);
  float* cWi = alloc(1400);
  float* cbi = alloc(280);
  float* cWm1 = alloc(473760);
  float* cbm1 = alloc(840);
  float* cg1 = alloc(840);
  float* cbe1 = alloc(840);
  float* cWm2 = alloc(235200);
  float* cbm2 = alloc(840);
  float* cg2 = alloc(840);
  float* cbe2 = alloc(840);
  float* cWu1 = alloc(470400);
  float* cbu1 = alloc(840);
  float* cg3 = alloc(840);
  float* cbe3 = alloc(840);
  float* cWu2 = alloc(235200);
  float* cbu2 = alloc(840);
  float* cg4 = alloc(840);
  float* cbe4 = alloc(840);
  float* cWmu = alloc(17920);
  float* cbmu = alloc(64);
  ush* W1ab = (ush*)alloc(248832);
  ush* W2t = (ush*)alloc(138240);
  ush* WU1t = (ush*)alloc(276480);
  ush* WU2t = (ush*)alloc(138240);
  float* h = alloc(NH);
  ush* hcat = (ush*)alloc(5824512);  // [20224][576] bf16; aliased by u2A
  ush* u2A = hcat;
  float* pqr = alloc(5824512);       // Pq bf16 [20224][576] / u1f fp32
  ush* Pq = (ush*)pqr;
  float* u1f = pqr;
  float* agg = alloc(NH);
  float* pooled = alloc((size_t)GG * HH);
  float* stats = alloc(8 * HH);
  float* ss = alloc(8 * HH);
  int* counts = (int*)alloc(NN);
  int* cursor = (int*)alloc(NN);
  int* offs = (int*)alloc(NN + 1);
  int* eids = (int*)alloc(EE);
  size_t baseB = off * 4;

  // full-E plan (single gather): T1 [E][288] + tmp2 [E][280], both bf16
  bool fullOK =
      (baseB + (size_t)EE * 288 * 2 + (size_t)EE * 280 * 2 + 64) <= ws_size;
  // fallback chunk plan (R12): EC=64000 keeps T1c L3-resident
  int EC = 6400, T2 = 6400;
  if (!fullOK) {
    const int ecs[4] = {64000, 32000, 12800, 6400};
    const int t2s[4] = {EE, 32000, 12800, 6400};
    for (int i = 0; i < 4; ++i) {
      size_t need = baseB + (size_t)ecs[i] * 288 * 2 + (size_t)t2s[i] * 280 * 2 + 64;
      if (need <= ws_size) { EC = ecs[i]; T2 = t2s[i]; break; }
    }
  }
  ush* T1c = (ush*)(w0 + off);                    // full: [E][288]; chunk: [EC][288]
  ush* tmp2 = T1c + (fullOK ? (size_t)EE * 288 : (size_t)EC * 288);
  bool stored = fullOK || (T2 == EE);
  int nch = fullOK ? 1 : (EE / EC);

  // ---- probe + convert ----
  probe_k<<<1, 256, 0, stream>>>(d_in[0], flag);
  struct Cv { const void* s; float* d; int n; };
  const Cv cv[22] = {
      {d_in[0], cx, NN * NFF},     {d_in[1], cea, EE * EFF},
      {d_in[4], cWi, NFF * HH},    {d_in[5], cbi, HH},
      {d_in[6], cWm1, LL * (2 * HH + EFF) * HH}, {d_in[7], cbm1, LL * HH},
      {d_in[8], cg1, LL * HH},     {d_in[9], cbe1, LL * HH},
      {d_in[10], cWm2, LL * HH * HH}, {d_in[11], cbm2, LL * HH},
      {d_in[12], cg2, LL * HH},    {d_in[13], cbe2, LL * HH},
      {d_in[14], cWu1, LL * 2 * HH * HH}, {d_in[15], cbu1, LL * HH},
      {d_in[16], cg3, LL * HH},    {d_in[17], cbe3, LL * HH},
      {d_in[18], cWu2, LL * HH * HH}, {d_in[19], cbu2, LL * HH},
      {d_in[20], cg4, LL * HH},    {d_in[21], cbe4, LL * HH},
      {d_in[22], cWmu, HH * ZZ},   {d_in[23], cbmu, ZZ}};
  for (int i = 0; i < 22; ++i)
    convert_k<<<(cv[i].n + 255) / 256, 256, 0, stream>>>(cv[i].s, cv[i].d, cv[i].n, flag);

  // bf16 transposed weights
  wt_ab_k<<<(3 * 576 * 288 + 255) / 256, 256, 0, stream>>>(cWm1, W1ab);
  wt_sq_k<<<(3 * 320 * 288 + 255) / 256, 256, 0, stream>>>(cWm2, W2t);
  wt_u1_k<<<(3 * 320 * 576 + 255) / 256, 256, 0, stream>>>(cWu1, WU1t);
  wt_sq_k<<<(3 * 320 * 288 + 255) / 256, 256, 0, stream>>>(cWu2, WU2t);

  // input layer: h = x @ Wi + bi (fp32)
  gemm_small_k<<<dim3(5, 313), 256, 0, stream>>>(cx, cWi, cbi, h, nullptr, NN,
                                                 NFF, HH, NFF, HH, HH, 0);
  // CSR over dst
  hipMemsetAsync(counts, 0, NN * sizeof(int), stream);
  hipMemsetAsync(cursor, 0, NN * sizeof(int), stream);
  hist_k<<<(EE + 255) / 256, 256, 0, stream>>>(dstp, counts);
  scan_k<<<1, 1024, 0, stream>>>(counts, offs, NN);
  fill_k<<<(EE + 255) / 256, 256, 0, stream>>>(dstp, offs, cursor, eids);

  int elemGrid = (int)((NH + 255) / 256);
  for (int l = 0; l < LL; ++l) {
    ush* Wab = W1ab + (size_t)l * 576 * 288;
    ush* W2l = W2t + (size_t)l * 320 * 288;
    ush* WU1l = WU1t + (size_t)l * 320 * 576;
    ush* WU2l = WU2t + (size_t)l * 320 * 288;
    const float* W1c = cWm1 + (size_t)l * 157920 + (size_t)560 * 280;
    float* st1 = stats;
    float* st2 = stats + 560;
    float* st3 = stats + 1120;
    float* st4 = stats + 1680;
    float* ss1 = ss;
    float* ss2 = ss + 560;
    float* ss3 = ss + 1120;
    float* ss4 = ss + 1680;
    hipMemsetAsync(stats, 0, 8 * HH * sizeof(float), stream);

    // hcat[:, 0:280] = bf16(h)
    hb_k<<<elemGrid, 256, 0, stream>>>(h, hcat);
    // Pq = hcat @ [W1a|W1b]  (M=20000, K=288, N=560)
    {
      MG g = {hcat, Wab, nullptr, Pq, nullptr, NN, 288, 560, 576, 288, 576};
      mgemm_k<1, 0><<<dim3(9, 157), 256, 0, stream>>>(g);
    }
    if (fullOK) {
      // SINGLE gather pass: raw T1 (incl b1) + fused stats1
      build_raw_k<<<EE / 256, 256, 0, stream>>>(eids, dstp, srcp, cea, Pq, W1c,
                                                cbm1 + l * HH, T1c, st1);
      // raw values include b1 -> extra = nullptr
      bn_finalize_k<<<1, 320, 0, stream>>>(st1, (float)EE, cg1 + l * HH,
                                           cbe1 + l * HH, nullptr, ss1,
                                           ss1 + HH);
      // streaming bn1+relu apply in place
      bn_apply_k<<<EE * 36 / 256, 256, 0, stream>>>(T1c, ss1, ss1 + HH);
      // one big GEMM: tmp2 = T1 @ W2 + b2, fused stats2
      {
        MG g = {T1c, W2l, cbm2 + l * HH, (void*)tmp2, st2,
                EE, 288, HH, 288, 288, HH};
        mgemm_k<1, 1><<<dim3(5, EE / 128), 256, 0, stream>>>(g);
      }
    } else {
      edge_stats_k<<<EE / 256, 256, 0, stream>>>(eids, dstp, srcp, cea, Pq,
                                                 W1c, cbm1 + l * HH, st1);
      bn_finalize_k<<<1, 320, 0, stream>>>(st1, (float)EE, cg1 + l * HH,
                                           cbe1 + l * HH, cbm1 + l * HH, ss1,
                                           ss1 + HH);
      for (int c = 0; c < nch; ++c) {
        int cb = c * EC;
        build_t1_k<<<EC / 32, 256, 0, stream>>>(eids, dstp, srcp, cea, Pq, W1c,
                                                ss1, ss1 + HH, T1c, cb);
        MG g = {T1c, W2l, cbm2 + l * HH,
                stored ? (void*)(tmp2 + (size_t)cb * HH) : (void*)tmp2, st2,
                EC, 288, HH, 288, 288, HH};
        mgemm_k<1, 1><<<dim3(5, EC / 128), 256, 0, stream>>>(g);
      }
    }
    bn_finalize_k<<<1, 320, 0, stream>>>(st2, (float)EE, cg2 + l * HH,
                                         cbe2 + l * HH, nullptr, ss2, ss2 + HH);
    // phase 2: aggregate relu(bn2(tmp2)) by dst
    hipMemsetAsync(agg, 0, NH * sizeof(float), stream);
    if (stored) {
      aggregate_k<<<NN, 256, 0, stream>>>(offs, tmp2, ss2, ss2 + HH, agg, 0, EE);
    } else {
      for (int c = 0; c < nch; ++c) {
        int cb = c * EC;
        build_t1_k<<<EC / 32, 256, 0, stream>>>(eids, dstp, srcp, cea, Pq, W1c,
                                                ss1, ss1 + HH, T1c, cb);
        MG g = {T1c, W2l, cbm2 + l * HH, (void*)tmp2, nullptr,
                EC, 288, HH, 288, 288, HH};
        mgemm_k<1, 0><<<dim3(5, EC / 128), 256, 0, stream>>>(g);
        aggregate_k<<<NN, 256, 0, stream>>>(offs, tmp2, ss2, ss2 + HH, agg, cb, cb + EC);
      }
    }
    agg2hcat_k<<<elemGrid, 256, 0, stream>>>(agg, hcat);
    // u1 = [h|agg] @ WU1 + bu1 (K=576), stats3; overwrites Pq region
    {
      MG g = {hcat, WU1l, cbu1 + l * HH, u1f, st3, NN, 576, HH, 576, 576, HH};
      mgemm_k<0, 1><<<dim3(5, 157), 256, 0, stream>>>(g);
    }
    bn_finalize_k<<<1, 320, 0, stream>>>(st3, (float)NN, cg3 + l * HH,
                                         cbe3 + l * HH, nullptr, ss3, ss3 + HH);
    // u2A = bf16(relu(bn3(u1)))  (overwrites hcat region)
    u2a_k<<<elemGrid, 256, 0, stream>>>(u1f, ss3, ss3 + HH, u2A);
    // u2 = u2A @ WU2 + bu2, stats4; C -> agg (fp32)
    {
      MG g = {u2A, WU2l, cbu2 + l * HH, agg, st4, NN, 288, HH, 288, 288, HH};
      mgemm_k<0, 1><<<dim3(5, 157), 256, 0, stream>>>(g);
    }
    bn_finalize_k<<<1, 320, 0, stream>>>(st4, (float)NN, cg4 + l * HH,
                                         cbe4 + l * HH, nullptr, ss4, ss4 + HH);
    residual_k<<<elemGrid, 256, 0, stream>>>(h, agg, ss4, ss4 + HH);
  }

  pool_k<<<dim3(GG, 5), 256, 0, stream>>>(h, batch, pooled);
  gemm_small_k<<<dim3(1, 1), 256, 0, stream>>>(pooled, cWmu, cbmu, d_out, flag,
                                               GG, HH, ZZ, HH, ZZ, ZZ, 1);
}

// Round 14
// 4272.456 us; speedup vs baseline: 1.2617x; 1.2617x over previous
//
#include <hip/hip_runtime.h>
#include <hip/hip_bf16.h>

#define NN 20000
#define EE 320000
#define GG 64
#define HH 280
#define NFF 5
#define EFF 4
#define LL 3
#define ZZ 64
#define BN_EPS 1e-5f

typedef __hip_bfloat16 bf;
typedef unsigned short ush;
typedef __attribute__((ext_vector_type(8))) short v8s;
typedef __attribute__((ext_vector_type(4))) float v4f;

__device__ __forceinline__ float us2f(ush u) {
  return __uint_as_float(((unsigned)u) << 16);
}
__device__ __forceinline__ ush f2us(float v) {
  bf b = __float2bfloat16(v);
  return *reinterpret_cast<ush*>(&b);
}
__device__ __forceinline__ int clampi(int v, int hi) {
  return v < 0 ? 0 : (v >= hi ? hi - 1 : v);
}

// ---------------------------------------------------------------------------
// dtype probe (x ~ N(0,1)): fp32 read as bf16 words -> implausible exponents
// ---------------------------------------------------------------------------
__global__ void probe_k(const void* __restrict__ x, int* __restrict__ flag) {
  __shared__ int sh[256];
  int tid = threadIdx.x;
  int cnt = 0;
  for (int i = tid; i < 2048; i += 256) {
    ush w = ((const ush*)x)[i];
    unsigned e = (w >> 7) & 0xFF;
    if (w != 0 && (e < 87 || e > 167)) cnt++;
  }
  sh[tid] = cnt;
  __syncthreads();
  for (int o = 128; o > 0; o >>= 1) {
    if (tid < o) sh[tid] += sh[tid + o];
    __syncthreads();
  }
  if (tid == 0) *flag = (sh[0] > 64) ? 1 : 0;
}

__global__ void convert_k(const void* __restrict__ src, float* __restrict__ dst,
                          int n, const int* __restrict__ flag) {
  int i = blockIdx.x * 256 + threadIdx.x;
  if (i < n) {
    if (*flag)
      dst[i] = ((const float*)src)[i];
    else
      dst[i] = us2f(((const ush*)src)[i]);
  }
}

// ---------------------------------------------------------------------------
// weight transpose builders (fp32 -> bf16 B^T padded with zeros)
// ---------------------------------------------------------------------------
__global__ void wt_ab_k(const float* __restrict__ W, ush* __restrict__ O) {
  int i = blockIdx.x * 256 + threadIdx.x;
  if (i >= 3 * 576 * 288) return;
  int l = i / 165888, r = i % 165888;
  int n = r / 288, k = r % 288;
  float v = 0.f;
  if (n < 560 && k < 280)
    v = (n < 280) ? W[(size_t)l * 157920 + (size_t)k * 280 + n]
                  : W[(size_t)l * 157920 + (size_t)(280 + k) * 280 + (n - 280)];
  O[i] = f2us(v);
}
__global__ void wt_sq_k(const float* __restrict__ W, ush* __restrict__ O) {
  int i = blockIdx.x * 256 + threadIdx.x;
  if (i >= 3 * 320 * 288) return;
  int l = i / 92160, r = i % 92160;
  int n = r / 288, k = r % 288;
  float v = (n < 280 && k < 280) ? W[(size_t)l * 78400 + (size_t)k * 280 + n] : 0.f;
  O[i] = f2us(v);
}
__global__ void wt_u1_k(const float* __restrict__ W, ush* __restrict__ O) {
  int i = blockIdx.x * 256 + threadIdx.x;
  if (i >= 3 * 320 * 576) return;
  int l = i / 184320, r = i % 184320;
  int n = r / 576, k = r % 576;
  float v = (n < 280 && k < 560) ? W[(size_t)l * 156800 + (size_t)k * 280 + n] : 0.f;
  O[i] = f2us(v);
}

// ---------------------------------------------------------------------------
// MFMA bf16 GEMM (best measured, 4.27ms config): BM=128, BN=64. B-tile
// staged in LDS once per 288-K-tile; A-frags global->VGPR direct, all 18 in
// flight; no barriers in K-loop.
// ---------------------------------------------------------------------------
struct MG {
  const ush* A;
  const ush* Bt;
  const float* bias;
  void* C;
  float* stats;
  int M, K, Nn, lda, ldb, ldc;
};

template <int CB, int ST>
__global__ __launch_bounds__(256) void mgemm_k(MG g) {
  __shared__ ush Bs[64][296];
  auto red = (float(*)[64])Bs;
  int t = threadIdx.x;
  int n0 = blockIdx.x * 64, m0 = blockIdx.y * 128;
  int lane = t & 63, wv = t >> 6;
  int lrow = lane & 15, quad = lane >> 4;
  int br = t >> 2;
  int bc = (t & 3) * 72;
  v4f acc[2][4];
#pragma unroll
  for (int gi = 0; gi < 2; ++gi)
#pragma unroll
    for (int ci = 0; ci < 4; ++ci) acc[gi][ci] = (v4f){0.f, 0.f, 0.f, 0.f};

  const ush* Arow[2];
  bool av[2];
#pragma unroll
  for (int gi = 0; gi < 2; ++gi) {
    int gm = m0 + (wv << 5) + (gi << 4) + lrow;
    av[gi] = gm < g.M;
    Arow[gi] = g.A + (size_t)gm * g.lda + (quad << 3);
  }
  const ush* Brow = g.Bt + (size_t)(n0 + br) * g.ldb + bc;
  uint4 zz = {0, 0, 0, 0};

  int ntile = g.K / 288;
  for (int tile = 0; tile < ntile; ++tile) {
    int k0 = tile * 288;
    uint4 aR[2][9];
#pragma unroll
    for (int kt = 0; kt < 9; ++kt)
#pragma unroll
      for (int gi = 0; gi < 2; ++gi)
        aR[gi][kt] = av[gi] ? *(const uint4*)(Arow[gi] + k0 + (kt << 5)) : zz;
    if (tile) __syncthreads();
#pragma unroll
    for (int i = 0; i < 9; ++i)
      *(uint4*)&Bs[br][bc + (i << 3)] = *(const uint4*)(Brow + k0 + (i << 3));
    __syncthreads();
#pragma unroll
    for (int kt = 0; kt < 9; ++kt) {
      v8s bq[4];
#pragma unroll
      for (int ci = 0; ci < 4; ++ci)
        bq[ci] = *(const v8s*)&Bs[(ci << 4) + lrow][(kt << 5) + (quad << 3)];
#pragma unroll
      for (int gi = 0; gi < 2; ++gi) {
        v8s af = *(v8s*)&aR[gi][kt];
#pragma unroll
        for (int ci = 0; ci < 4; ++ci)
          acc[gi][ci] = __builtin_amdgcn_mfma_f32_16x16x32_bf16(
              af, bq[ci], acc[gi][ci], 0, 0, 0);
      }
    }
  }

  float bj[4];
#pragma unroll
  for (int ci = 0; ci < 4; ++ci) {
    int gn = n0 + (ci << 4) + lrow;
    bj[ci] = (g.bias && gn < g.Nn) ? g.bias[gn] : 0.f;
  }
#pragma unroll
  for (int gi = 0; gi < 2; ++gi)
#pragma unroll
    for (int ci = 0; ci < 4; ++ci)
#pragma unroll
      for (int r = 0; r < 4; ++r) {
        int gm = m0 + (wv << 5) + (gi << 4) + (quad << 2) + r;
        int gn = n0 + (ci << 4) + lrow;
        float v = acc[gi][ci][r] + bj[ci];
        bool ok = (gm < g.M) && (gn < g.Nn);
        if (ok) {
          size_t idx = (size_t)gm * g.ldc + gn;
          if (CB)
            ((ush*)g.C)[idx] = f2us(v);
          else
            ((float*)g.C)[idx] = v;
        }
        acc[gi][ci][r] = ok ? v : 0.f;
      }
  if (ST) {
    int rowg = (wv << 2) | quad;
    __syncthreads();
#pragma unroll
    for (int ci = 0; ci < 4; ++ci) {
      float s = 0.f;
#pragma unroll
      for (int gi = 0; gi < 2; ++gi)
#pragma unroll
        for (int r = 0; r < 4; ++r) s += acc[gi][ci][r];
      red[rowg][(ci << 4) | lrow] = s;
    }
    __syncthreads();
    if (t < 64) {
      float s = 0.f;
#pragma unroll
      for (int r = 0; r < 16; ++r) s += red[r][t];
      int gn = n0 + t;
      if (gn < g.Nn) atomicAdd(&g.stats[gn], s);
    }
    __syncthreads();
#pragma unroll
    for (int ci = 0; ci < 4; ++ci) {
      float s = 0.f;
#pragma unroll
      for (int gi = 0; gi < 2; ++gi)
#pragma unroll
        for (int r = 0; r < 4; ++r) s += acc[gi][ci][r] * acc[gi][ci][r];
      red[rowg][(ci << 4) | lrow] = s;
    }
    __syncthreads();
    if (t < 64) {
      float s = 0.f;
#pragma unroll
      for (int r = 0; r < 16; ++r) s += red[r][t];
      int gn = n0 + t;
      if (gn < g.Nn) atomicAdd(&g.stats[HH + gn], s);
    }
  }
}

// ---------------------------------------------------------------------------
// small fp32 GEMM (input layer, final head). 64x64 tile.
// ---------------------------------------------------------------------------
__global__ __launch_bounds__(256) void gemm_small_k(
    const float* __restrict__ A, const float* __restrict__ B,
    const float* __restrict__ bias, void* __restrict__ C,
    const int* __restrict__ flag, int M, int K, int Nn, int lda, int ldb,
    int ldc, int outmode) {
  __shared__ alignas(16) float As[16][68];
  __shared__ alignas(16) float Bsm[16][68];
  int tid = threadIdx.x;
  int n0 = blockIdx.x * 64, m0 = blockIdx.y * 64;
  int tx = tid & 15, ty = tid >> 4;
  int am = tid >> 2, akq = (tid & 3) << 2;
  int bk = tid >> 4, bn = (tid & 15) << 2;
  float acc[4][4] = {};
  int gmA = m0 + am;
  int nkt = (K + 15) >> 4;
  for (int kt = 0; kt < nkt; ++kt) {
    int k0 = kt << 4;
#pragma unroll
    for (int i = 0; i < 4; ++i) {
      int gk = k0 + akq + i;
      As[akq + i][am] = (gmA < M && gk < K) ? A[(size_t)gmA * lda + gk] : 0.f;
    }
    {
      int gk = k0 + bk;
      bool kin = gk < K;
#pragma unroll
      for (int j = 0; j < 4; ++j) {
        int gn = n0 + bn + j;
        Bsm[bk][bn + j] = (kin && gn < Nn) ? B[(size_t)gk * ldb + gn] : 0.f;
      }
    }
    __syncthreads();
#pragma unroll
    for (int kk = 0; kk < 16; ++kk) {
      float4 a4 = *(const float4*)&As[kk][ty << 2];
      float4 b4 = *(const float4*)&Bsm[kk][tx << 2];
      float av[4] = {a4.x, a4.y, a4.z, a4.w};
      float bv[4] = {b4.x, b4.y, b4.z, b4.w};
#pragma unroll
      for (int i = 0; i < 4; ++i)
#pragma unroll
        for (int j = 0; j < 4; ++j) acc[i][j] = fmaf(av[i], bv[j], acc[i][j]);
    }
    __syncthreads();
  }
  int ofl = outmode ? *flag : -1;
#pragma unroll
  for (int i = 0; i < 4; ++i) {
    int gm = m0 + (ty << 2) + i;
    if (gm < M) {
#pragma unroll
      for (int j = 0; j < 4; ++j) {
        int gn = n0 + (tx << 2) + j;
        if (gn < Nn) {
          float v = acc[i][j] + (bias ? bias[gn] : 0.f);
          size_t idx = (size_t)gm * ldc + gn;
          if (outmode == 0)
            ((float*)C)[idx] = v;
          else if (ofl)
            ((float*)C)[idx] = v;
          else
            ((ush*)C)[idx] = f2us(v);
        }
      }
    }
  }
}

// ---------------------------------------------------------------------------
// BN1 stats over edges (CSR order), 256 edges/block, x4-unrolled gathers
// ---------------------------------------------------------------------------
__global__ __launch_bounds__(256) void edge_stats_k(
    const int* __restrict__ eids, const int* __restrict__ dst,
    const int* __restrict__ src, const float* __restrict__ ea,
    const ush* __restrict__ Pq, const float* __restrict__ W1c,
    const float* __restrict__ b1, float* __restrict__ stats) {
  __shared__ int dstl[256], srcl[256];
  __shared__ float4 eal[256];
  __shared__ float w1cs[4 * HH];
  __shared__ float b1s[HH];
  int tid = threadIdx.x;
  int e0 = blockIdx.x * 256;
  {
    int e = clampi(eids[e0 + tid], EE);
    dstl[tid] = clampi(dst[e], NN);
    srcl[tid] = clampi(src[e], NN);
    eal[tid] = *(const float4*)(ea + (size_t)e * 4);
  }
  for (int i = tid; i < 4 * HH; i += 256) w1cs[i] = W1c[i];
  for (int i = tid; i < HH; i += 256) b1s[i] = b1[i];
  __syncthreads();
  int c0 = tid, c1 = tid + 256;
  bool has1 = c1 < HH;
  float w0x = w1cs[c0], w0y = w1cs[HH + c0], w0z = w1cs[2 * HH + c0],
        w0w = w1cs[3 * HH + c0], b0v = b1s[c0];
  float w1x = 0.f, w1y = 0.f, w1z = 0.f, w1w = 0.f, b1v = 0.f;
  if (has1) {
    w1x = w1cs[c1]; w1y = w1cs[HH + c1]; w1z = w1cs[2 * HH + c1];
    w1w = w1cs[3 * HH + c1]; b1v = b1s[c1];
  }
  float s0 = 0.f, q0 = 0.f, s1 = 0.f, q1 = 0.f;
  for (int e = 0; e < 256; e += 4) {
    ush pd[4], ps[4], pd2[4], ps2[4];
#pragma unroll
    for (int j = 0; j < 4; ++j) {
      size_t bd = (size_t)dstl[e + j] * 576, bs = (size_t)srcl[e + j] * 576 + 280;
      pd[j] = Pq[bd + c0];
      ps[j] = Pq[bs + c0];
      if (has1) {
        pd2[j] = Pq[bd + c1];
        ps2[j] = Pq[bs + c1];
      }
    }
#pragma unroll
    for (int j = 0; j < 4; ++j) {
      float4 ev = eal[e + j];
      float tv = us2f(pd[j]) + us2f(ps[j]) + ev.x * w0x + ev.y * w0y +
                 ev.z * w0z + ev.w * w0w + b0v;
      s0 += tv;
      q0 += tv * tv;
      if (has1) {
        float t2 = us2f(pd2[j]) + us2f(ps2[j]) + ev.x * w1x + ev.y * w1y +
                   ev.z * w1z + ev.w * w1w + b1v;
        s1 += t2;
        q1 += t2 * t2;
      }
    }
  }
  atomicAdd(&stats[c0], s0);
  atomicAdd(&stats[HH + c0], q0);
  if (has1) {
    atomicAdd(&stats[c1], s1);
    atomicAdd(&stats[HH + c1], q1);
  }
}

__global__ void bn_finalize_k(const float* __restrict__ stats, float cnt,
                              const float* __restrict__ gw,
                              const float* __restrict__ bw,
                              const float* __restrict__ extra,
                              float* __restrict__ scale,
                              float* __restrict__ shift) {
  int c = threadIdx.x;
  if (c < HH) {
    float m = stats[c] / cnt;
    float v = stats[HH + c] / cnt - m * m;
    v = v < 0.f ? 0.f : v;
    float r = rsqrtf(v + BN_EPS);
    float sc = gw[c] * r;
    float sh = bw[c] - sc * m + (extra ? sc * extra[c] : 0.f);
    scale[c] = sc;
    shift[c] = sh;
  }
}

// ---------------------------------------------------------------------------
// CSR build over dst
// ---------------------------------------------------------------------------
__global__ void hist_k(const int* __restrict__ dst, int* __restrict__ counts) {
  int e = blockIdx.x * 256 + threadIdx.x;
  if (e < EE) atomicAdd(&counts[clampi(dst[e], NN)], 1);
}

__global__ __launch_bounds__(1024) void scan_k(const int* __restrict__ counts,
                                               int* __restrict__ offs, int n) {
  __shared__ int buf[1024];
  __shared__ int running;
  int tid = threadIdx.x;
  if (tid == 0) running = 0;
  __syncthreads();
  for (int base = 0; base < n; base += 1024) {
    int v = (base + tid < n) ? counts[base + tid] : 0;
    buf[tid] = v;
    __syncthreads();
    for (int off = 1; off < 1024; off <<= 1) {
      int t = (tid >= off) ? buf[tid - off] : 0;
      __syncthreads();
      buf[tid] += t;
      __syncthreads();
    }
    int incl = buf[tid];
    if (base + tid < n) offs[base + tid] = running + incl - v;
    __syncthreads();
    if (tid == 1023) running += incl;
    __syncthreads();
  }
  if (tid == 0) offs[n] = running;
}

__global__ void fill_k(const int* __restrict__ dst, const int* __restrict__ offs,
                       int* __restrict__ cursor, int* __restrict__ eids) {
  int e = blockIdx.x * 256 + threadIdx.x;
  if (e < EE) {
    int n = clampi(dst[e], NN);
    int pos = atomicAdd(&cursor[n], 1);
    int idx = offs[n] + pos;
    if (idx >= 0 && idx < EE) eids[idx] = e;
  }
}

// ---------------------------------------------------------------------------
// T1 builder (CSR order): T1c[r-cb][c] = relu(bn1(P[d]+Q[s]+ea@W1c)) bf16
// ---------------------------------------------------------------------------
__global__ __launch_bounds__(256) void build_t1_k(
    const int* __restrict__ eids, const int* __restrict__ dst,
    const int* __restrict__ src, const float* __restrict__ ea,
    const ush* __restrict__ Pq, const float* __restrict__ W1c,
    const float* __restrict__ sc, const float* __restrict__ sh,
    ush* __restrict__ T1, int cb) {
  __shared__ float scs[HH], shs[HH], w1[4 * HH];
  int t = threadIdx.x;
  for (int i = t; i < HH; i += 256) { scs[i] = sc[i]; shs[i] = sh[i]; }
  for (int i = t; i < 4 * HH; i += 256) w1[i] = W1c[i];
  __syncthreads();
  int base = blockIdx.x * 32;
  int c2 = t + 256;
  bool h2 = c2 < HH;
  for (int i = 0; i < 32; ++i) {
    int r = cb + base + i;
    int e = clampi(eids[r], EE);
    int d = clampi(dst[e], NN), s = clampi(src[e], NN);
    float4 ev = *(const float4*)(ea + (size_t)e * 4);
    size_t pd = (size_t)d * 576, ps = (size_t)s * 576 + 280;
    size_t orow = (size_t)(base + i) * 288;
    {
      int c = t;
      float v = us2f(Pq[pd + c]) + us2f(Pq[ps + c]) + ev.x * w1[c] +
                ev.y * w1[HH + c] + ev.z * w1[2 * HH + c] + ev.w * w1[3 * HH + c];
      v = fmaf(scs[c], v, shs[c]);
      T1[orow + c] = f2us(v > 0.f ? v : 0.f);
    }
    if (h2) {
      int c = c2;
      float v = us2f(Pq[pd + c]) + us2f(Pq[ps + c]) + ev.x * w1[c] +
                ev.y * w1[HH + c] + ev.z * w1[2 * HH + c] + ev.w * w1[3 * HH + c];
      v = fmaf(scs[c], v, shs[c]);
      T1[orow + c] = f2us(v > 0.f ? v : 0.f);
    }
  }
}

// ---------------------------------------------------------------------------
// CSR-streamed aggregate: agg[n][c] += sum_{r in [rs,re)∩[e0,e1)} relu(bn2(tmp2))
// ---------------------------------------------------------------------------
__global__ __launch_bounds__(256) void aggregate_k(
    const int* __restrict__ offs, const ush* __restrict__ tmp2,
    const float* __restrict__ scale, const float* __restrict__ shift,
    float* __restrict__ agg, int e0, int e1) {
  int n = blockIdx.x;
  int rs = offs[n], re = offs[n + 1];
  if (rs < e0) rs = e0;
  if (re > e1) re = e1;
  if (rs >= re) return;
  int t = threadIdx.x;
  int c2 = t + 256;
  bool h2 = c2 < HH;
  float a0 = 0.f, a1 = 0.f;
  float sc0 = scale[t], sh0 = shift[t];
  float sc1 = h2 ? scale[c2] : 0.f, sh1 = h2 ? shift[c2] : 0.f;
  for (int r = rs; r < re; ++r) {
    const ush* row = tmp2 + (size_t)(r - e0) * HH;
    float v0 = fmaf(sc0, us2f(row[t]), sh0);
    a0 += v0 > 0.f ? v0 : 0.f;
    if (h2) {
      float v1 = fmaf(sc1, us2f(row[c2]), sh1);
      a1 += v1 > 0.f ? v1 : 0.f;
    }
  }
  agg[(size_t)n * HH + t] += a0;
  if (h2) agg[(size_t)n * HH + c2] += a1;
}

// ---------------------------------------------------------------------------
// elementwise helpers
// ---------------------------------------------------------------------------
__global__ void hb_k(const float* __restrict__ h, ush* __restrict__ hcat) {
  int i = blockIdx.x * 256 + threadIdx.x;
  if (i < NN * HH) {
    int n = i / HH, c = i % HH;
    hcat[(size_t)n * 576 + c] = f2us(h[i]);
  }
}
__global__ void agg2hcat_k(const float* __restrict__ agg, ush* __restrict__ hcat) {
  int i = blockIdx.x * 256 + threadIdx.x;
  if (i < NN * HH) {
    int n = i / HH, c = i % HH;
    hcat[(size_t)n * 576 + 280 + c] = f2us(agg[i]);
  }
}
__global__ void u2a_k(const float* __restrict__ u1, const float* __restrict__ sc,
                      const float* __restrict__ sh, ush* __restrict__ u2A) {
  int i = blockIdx.x * 256 + threadIdx.x;
  if (i < NN * HH) {
    int n = i / HH, c = i % HH;
    float v = fmaf(sc[c], u1[i], sh[c]);
    u2A[(size_t)n * 288 + c] = f2us(v > 0.f ? v : 0.f);
  }
}
__global__ void residual_k(float* __restrict__ h, const float* __restrict__ u2,
                           const float* __restrict__ scale,
                           const float* __restrict__ shift) {
  int i = blockIdx.x * 256 + threadIdx.x;
  if (i < NN * HH) {
    int c = i % HH;
    float v = fmaf(scale[c], u2[i], shift[c]);
    h[i] += v > 0.f ? v : 0.f;
  }
}

__device__ __forceinline__ int lowerb(const int* a, int n, int key) {
  int lo = 0, hi = n;
  while (lo < hi) {
    int mid = (lo + hi) >> 1;
    if (a[mid] < key) lo = mid + 1; else hi = mid;
  }
  return lo;
}

// pooled mean per (graph, 56-col chunk); grid (GG, 5), 256 threads
__global__ __launch_bounds__(256) void pool_k(const float* __restrict__ h,
                                              const int* __restrict__ batch,
                                              float* __restrict__ pooled) {
  __shared__ float red[4][56];
  int gid = blockIdx.x, cc = blockIdx.y;
  int start = lowerb(batch, NN, gid);
  int end = lowerb(batch, NN, gid + 1);
  int cnt = end - start;
  float inv = 1.f / (float)(cnt > 1 ? cnt : 1);
  int grp = threadIdx.x >> 6, ci = threadIdx.x & 63;
  if (ci < 56) {
    int col = cc * 56 + ci;
    float s = 0.f;
    for (int n = start + grp; n < end; n += 4) s += h[(size_t)n * HH + col];
    red[grp][ci] = s;
  }
  __syncthreads();
  if (threadIdx.x < 56) {
    float s = red[0][threadIdx.x] + red[1][threadIdx.x] +
              red[2][threadIdx.x] + red[3][threadIdx.x];
    pooled[(size_t)gid * HH + cc * 56 + threadIdx.x] = s * inv;
  }
}

// ---------------------------------------------------------------------------
extern "C" void kernel_launch(void* const* d_in, const int* in_sizes, int n_in,
                              void* d_out, int out_size, void* d_ws,
                              size_t ws_size, hipStream_t stream) {
  const int* eidx = (const int*)d_in[2];
  const int* batch = (const int*)d_in[3];
  const int* srcp = eidx;
  const int* dstp = eidx + EE;
  size_t NH = (size_t)NN * HH;

  // ---- workspace layout ----
  float* w0 = (float*)d_ws;
  size_t off = 0;
  auto alloc = [&](size_t n) {
    float* p = w0 + off;
    off += (n + 3) & ~(size_t)3;
    return p;
  };
  int* flag = (int*)alloc(4);
  float* cx = alloc(100000);
  float* cea = alloc(1280000);
  float* cWi = alloc(1400);
  float* cbi = alloc(280);
  float* cWm1 = alloc(473760);
  float* cbm1 = alloc(840);
  float* cg1 = alloc(840);
  float* cbe1 = alloc(840);
  float* cWm2 = alloc(235200);
  float* cbm2 = alloc(840);
  float* cg2 = alloc(840);
  float* cbe2 = alloc(840);
  float* cWu1 = alloc(470400);
  float* cbu1 = alloc(840);
  float* cg3 = alloc(840);
  float* cbe3 = alloc(840);
  float* cWu2 = alloc(235200);
  float* cbu2 = alloc(840);
  float* cg4 = alloc(840);
  float* cbe4 = alloc(840);
  float* cWmu = alloc(17920);
  float* cbmu = alloc(64);
  ush* W1ab = (ush*)alloc(248832);
  ush* W2t = (ush*)alloc(138240);
  ush* WU1t = (ush*)alloc(276480);
  ush* WU2t = (ush*)alloc(138240);
  float* h = alloc(NH);
  ush* hcat = (ush*)alloc(5824512);  // [20224][576] bf16; aliased by u2A
  ush* u2A = hcat;
  float* pqr = alloc(5824512);       // Pq bf16 [20224][576] / u1f fp32
  ush* Pq = (ush*)pqr;
  float* u1f = pqr;
  float* agg = alloc(NH);
  float* pooled = alloc((size_t)GG * HH);
  float* stats = alloc(8 * HH);
  float* ss = alloc(8 * HH);
  int* counts = (int*)alloc(NN);
  int* cursor = (int*)alloc(NN);
  int* offs = (int*)alloc(NN + 1);
  int* eids = (int*)alloc(EE);
  size_t baseB = off * 4;

  // chunk plan (round-8 best): EC=64000 keeps T1c (37MB) L3-resident
  int EC = 6400, T2 = 6400;
  {
    const int ecs[5] = {64000, 64000, 32000, 12800, 6400};
    const int t2s[5] = {EE, 64000, 32000, 12800, 6400};
    for (int i = 0; i < 5; ++i) {
      size_t need = baseB + (size_t)ecs[i] * 288 * 2 + (size_t)t2s[i] * 280 * 2 + 64;
      if (need <= ws_size) { EC = ecs[i]; T2 = t2s[i]; break; }
    }
  }
  ush* T1c = (ush*)(w0 + off);
  ush* tmp2 = T1c + (size_t)EC * 288;
  bool stored = (T2 == EE);
  int nch = EE / EC;

  // ---- probe + convert ----
  probe_k<<<1, 256, 0, stream>>>(d_in[0], flag);
  struct Cv { const void* s; float* d; int n; };
  const Cv cv[22] = {
      {d_in[0], cx, NN * NFF},     {d_in[1], cea, EE * EFF},
      {d_in[4], cWi, NFF * HH},    {d_in[5], cbi, HH},
      {d_in[6], cWm1, LL * (2 * HH + EFF) * HH}, {d_in[7], cbm1, LL * HH},
      {d_in[8], cg1, LL * HH},     {d_in[9], cbe1, LL * HH},
      {d_in[10], cWm2, LL * HH * HH}, {d_in[11], cbm2, LL * HH},
      {d_in[12], cg2, LL * HH},    {d_in[13], cbe2, LL * HH},
      {d_in[14], cWu1, LL * 2 * HH * HH}, {d_in[15], cbu1, LL * HH},
      {d_in[16], cg3, LL * HH},    {d_in[17], cbe3, LL * HH},
      {d_in[18], cWu2, LL * HH * HH}, {d_in[19], cbu2, LL * HH},
      {d_in[20], cg4, LL * HH},    {d_in[21], cbe4, LL * HH},
      {d_in[22], cWmu, HH * ZZ},   {d_in[23], cbmu, ZZ}};
  for (int i = 0; i < 22; ++i)
    convert_k<<<(cv[i].n + 255) / 256, 256, 0, stream>>>(cv[i].s, cv[i].d, cv[i].n, flag);

  // bf16 transposed weights
  wt_ab_k<<<(3 * 576 * 288 + 255) / 256, 256, 0, stream>>>(cWm1, W1ab);
  wt_sq_k<<<(3 * 320 * 288 + 255) / 256, 256, 0, stream>>>(cWm2, W2t);
  wt_u1_k<<<(3 * 320 * 576 + 255) / 256, 256, 0, stream>>>(cWu1, WU1t);
  wt_sq_k<<<(3 * 320 * 288 + 255) / 256, 256, 0, stream>>>(cWu2, WU2t);

  // input layer: h = x @ Wi + bi (fp32)
  gemm_small_k<<<dim3(5, 313), 256, 0, stream>>>(cx, cWi, cbi, h, nullptr, NN,
                                                 NFF, HH, NFF, HH, HH, 0);
  // CSR over dst
  hipMemsetAsync(counts, 0, NN * sizeof(int), stream);
  hipMemsetAsync(cursor, 0, NN * sizeof(int), stream);
  hist_k<<<(EE + 255) / 256, 256, 0, stream>>>(dstp, counts);
  scan_k<<<1, 1024, 0, stream>>>(counts, offs, NN);
  fill_k<<<(EE + 255) / 256, 256, 0, stream>>>(dstp, offs, cursor, eids);

  int elemGrid = (int)((NH + 255) / 256);
  for (int l = 0; l < LL; ++l) {
    ush* Wab = W1ab + (size_t)l * 576 * 288;
    ush* W2l = W2t + (size_t)l * 320 * 288;
    ush* WU1l = WU1t + (size_t)l * 320 * 576;
    ush* WU2l = WU2t + (size_t)l * 320 * 288;
    const float* W1c = cWm1 + (size_t)l * 157920 + (size_t)560 * 280;
    float* st1 = stats;
    float* st2 = stats + 560;
    float* st3 = stats + 1120;
    float* st4 = stats + 1680;
    float* ss1 = ss;
    float* ss2 = ss + 560;
    float* ss3 = ss + 1120;
    float* ss4 = ss + 1680;
    hipMemsetAsync(stats, 0, 8 * HH * sizeof(float), stream);

    // hcat[:, 0:280] = bf16(h)
    hb_k<<<elemGrid, 256, 0, stream>>>(h, hcat);
    // Pq = hcat @ [W1a|W1b]  (M=20000, K=288, N=560)
    {
      MG g = {hcat, Wab, nullptr, Pq, nullptr, NN, 288, 560, 576, 288, 576};
      mgemm_k<1, 0><<<dim3(9, 157), 256, 0, stream>>>(g);
    }
    edge_stats_k<<<EE / 256, 256, 0, stream>>>(eids, dstp, srcp, cea, Pq, W1c,
                                               cbm1 + l * HH, st1);
    bn_finalize_k<<<1, 320, 0, stream>>>(st1, (float)EE, cg1 + l * HH,
                                         cbe1 + l * HH, cbm1 + l * HH, ss1,
                                         ss1 + HH);
    // phase 1: tmp2 = T1 @ W2 + b2 (chunked), accumulate stats2
    for (int c = 0; c < nch; ++c) {
      int cb = c * EC;
      build_t1_k<<<EC / 32, 256, 0, stream>>>(eids, dstp, srcp, cea, Pq, W1c,
                                              ss1, ss1 + HH, T1c, cb);
      MG g = {T1c, W2l, cbm2 + l * HH,
              stored ? (void*)(tmp2 + (size_t)cb * HH) : (void*)tmp2, st2,
              EC, 288, HH, 288, 288, HH};
      mgemm_k<1, 1><<<dim3(5, EC / 128), 256, 0, stream>>>(g);
    }
    bn_finalize_k<<<1, 320, 0, stream>>>(st2, (float)EE, cg2 + l * HH,
                                         cbe2 + l * HH, nullptr, ss2, ss2 + HH);
    // phase 2: aggregate relu(bn2(tmp2)) by dst
    hipMemsetAsync(agg, 0, NH * sizeof(float), stream);
    if (stored) {
      aggregate_k<<<NN, 256, 0, stream>>>(offs, tmp2, ss2, ss2 + HH, agg, 0, EE);
    } else {
      for (int c = 0; c < nch; ++c) {
        int cb = c * EC;
        build_t1_k<<<EC / 32, 256, 0, stream>>>(eids, dstp, srcp, cea, Pq, W1c,
                                                ss1, ss1 + HH, T1c, cb);
        MG g = {T1c, W2l, cbm2 + l * HH, (void*)tmp2, nullptr,
                EC, 288, HH, 288, 288, HH};
        mgemm_k<1, 0><<<dim3(5, EC / 128), 256, 0, stream>>>(g);
        aggregate_k<<<NN, 256, 0, stream>>>(offs, tmp2, ss2, ss2 + HH, agg, cb, cb + EC);
      }
    }
    agg2hcat_k<<<elemGrid, 256, 0, stream>>>(agg, hcat);
    // u1 = [h|agg] @ WU1 + bu1 (K=576), stats3; overwrites Pq region
    {
      MG g = {hcat, WU1l, cbu1 + l * HH, u1f, st3, NN, 576, HH, 576, 576, HH};
      mgemm_k<0, 1><<<dim3(5, 157), 256, 0, stream>>>(g);
    }
    bn_finalize_k<<<1, 320, 0, stream>>>(st3, (float)NN, cg3 + l * HH,
                                         cbe3 + l * HH, nullptr, ss3, ss3 + HH);
    // u2A = bf16(relu(bn3(u1)))  (overwrites hcat region)
    u2a_k<<<elemGrid, 256, 0, stream>>>(u1f, ss3, ss3 + HH, u2A);
    // u2 = u2A @ WU2 + bu2, stats4; C -> agg (fp32)
    {
      MG g = {u2A, WU2l, cbu2 + l * HH, agg, st4, NN, 288, HH, 288, 288, HH};
      mgemm_k<0, 1><<<dim3(5, 157), 256, 0, stream>>>(g);
    }
    bn_finalize_k<<<1, 320, 0, stream>>>(st4, (float)NN, cg4 + l * HH,
                                         cbe4 + l * HH, nullptr, ss4, ss4 + HH);
    residual_k<<<elemGrid, 256, 0, stream>>>(h, agg, ss4, ss4 + HH);
  }

  pool_k<<<dim3(GG, 5), 256, 0, stream>>>(h, batch, pooled);
  gemm_small_k<<<dim3(1, 1), 256, 0, stream>>>(pooled, cWmu, cbmu, d_out, flag,
                                               GG, HH, ZZ, HH, ZZ, ZZ, 1);
}